// Round 1
// baseline (85.752 us; speedup 1.0000x reference)
//
#include <hip/hip_runtime.h>
#include <math.h>

// GATLayerTemporal: N=4, H=16, W=16, T=32, V=32, HW=256
// Key identity: the (N,V,V,T,2HW) pairwise tensor never needs to exist.
//   e[n,i,j,2m]   = s[n,i,m]   (independent of j)
//   e[n,i,j,2m+1] = s[n,j,m]   (independent of i)
// where s[n,v,m] = sum_{w<16,t<32} Wh[n,v,m*16+w,t] * a[w*32+t]  (contiguous dot of 512).
//
// ws layout (floats):
//   Wh   [N][V][HW][T]   1048576
//   WhT  [N][T][HW][V]   1048576   (transposed copy for coalesced staging in k_out)
//   u    [N*V][16]       2048      (leaky-relu'd s)
//   mx   [N*V]           128
//   E    [N*V]           128       (sum exp(u - mx))
//   adjn [V*V]           1024

#define ALPHA 0.2f

__global__ __launch_bounds__(256) void k_adjnorm(const float* __restrict__ B,
                                                 float* __restrict__ adjn_g) {
    __shared__ float nrm[1024];
    __shared__ float red[64];
    __shared__ float dis[32];
    __shared__ float mnmx[2];
    int tid = threadIdx.x;
    float vals[4];
    float lmn = 1e30f, lmx = -1e30f;
    for (int k = 0; k < 4; ++k) {
        int e = tid + 256 * k;
        float x = B[e] + 1e-6f + (((e >> 5) == (e & 31)) ? 1.0f : 0.0f);
        vals[k] = x;
        lmn = fminf(lmn, x);
        lmx = fmaxf(lmx, x);
    }
    // wave (64-lane) butterfly reduce
    for (int m = 1; m < 64; m <<= 1) {
        lmn = fminf(lmn, __shfl_xor(lmn, m));
        lmx = fmaxf(lmx, __shfl_xor(lmx, m));
    }
    int wid = tid >> 6;
    if ((tid & 63) == 0) { red[wid] = lmn; red[32 + wid] = lmx; }
    __syncthreads();
    if (tid == 0) {
        float mn = fminf(fminf(red[0], red[1]), fminf(red[2], red[3]));
        float mx = fmaxf(fmaxf(red[32], red[33]), fmaxf(red[34], red[35]));
        mnmx[0] = mn; mnmx[1] = mx;
    }
    __syncthreads();
    float mn = mnmx[0];
    float inv = 1.0f / (mnmx[1] - mn);
    for (int k = 0; k < 4; ++k) {
        int e = tid + 256 * k;
        nrm[e] = (vals[k] - mn) * inv;
    }
    __syncthreads();
    if (tid < 32) {
        float rs = 0.f;
        for (int i = 0; i < 32; ++i) rs += nrm[tid * 32 + i];
        dis[tid] = 1.0f / sqrtf(rs);
    }
    __syncthreads();
    for (int k = 0; k < 4; ++k) {
        int e = tid + 256 * k;
        adjn_g[e] = nrm[e] * dis[e >> 5] * dis[e & 31];
    }
}

// One block per (n,c): Wh[n,v,c,t'] = sum_t h[n,c,t,v] * W[t,t']
__global__ __launch_bounds__(256) void k_wh(const float* __restrict__ h,
                                            const float* __restrict__ Wm,
                                            float* __restrict__ Wh,
                                            float* __restrict__ WhT) {
    __shared__ float ht[1024]; // [t][v]
    __shared__ float Wl[1024]; // [t][tp]
    int tid = threadIdx.x;
    int bid = blockIdx.x;
    int n = bid >> 8, c = bid & 255;
    const float4* hsrc = (const float4*)(h + ((size_t)(n * 256 + c)) * 1024);
    ((float4*)ht)[tid] = hsrc[tid];
    ((float4*)Wl)[tid] = ((const float4*)Wm)[tid];
    __syncthreads();
    int tp = tid & 31, v0 = tid >> 5;
    for (int p = 0; p < 4; ++p) {
        int v = v0 + 8 * p;
        float acc = 0.f;
#pragma unroll
        for (int t = 0; t < 32; ++t)
            acc = fmaf(ht[t * 32 + v], Wl[t * 32 + tp], acc);
        Wh[(((size_t)(n * 32 + v)) * 256 + c) * 32 + tp] = acc;
        WhT[(((size_t)(n * 32 + tp)) * 256 + c) * 32 + v] = acc;
    }
}

// One block per (n,v): s[m] = dot(Wh[n,v,m*16..m*16+16, :], a[0..512)); then u, mx, E
__global__ __launch_bounds__(256) void k_softstats(const float* __restrict__ Wh,
                                                   const float* __restrict__ a,
                                                   float* __restrict__ u_g,
                                                   float* __restrict__ mx_g,
                                                   float* __restrict__ E_g) {
    __shared__ float su[16];
    int tid = threadIdx.x;
    int nv = blockIdx.x;
    int m = tid >> 4, l = tid & 15;
    const float* base = Wh + (size_t)nv * 8192 + m * 512;
    float acc = 0.f;
    for (int k = 0; k < 32; ++k) {
        int e = k * 16 + l;
        acc = fmaf(base[e], a[e], acc);
    }
    for (int msk = 1; msk < 16; msk <<= 1) acc += __shfl_xor(acc, msk, 16);
    float u = acc > 0.f ? acc : ALPHA * acc;
    if (l == 0) su[m] = u;
    __syncthreads();
    if (tid < 16) {
        float uu = su[tid];
        float mxv = uu;
        for (int msk = 1; msk < 16; msk <<= 1) mxv = fmaxf(mxv, __shfl_xor(mxv, msk, 16));
        float ex = expf(uu - mxv);
        float es = ex;
        for (int msk = 1; msk < 16; msk <<= 1) es += __shfl_xor(es, msk, 16);
        u_g[nv * 16 + tid] = uu;
        if (tid == 0) { mx_g[nv] = mxv; E_g[nv] = es; }
    }
}

// One block per (n,t'): out[n,c,t',i] = elu( sum_j G[i,j] * WhT[n,t',c,j] )
//   G[i,j] = sum_v adjn[v,i] * att[n,v,j,t']
__global__ __launch_bounds__(256) void k_out(const float* __restrict__ WhT,
                                             const float* __restrict__ u_g,
                                             const float* __restrict__ mx_g,
                                             const float* __restrict__ E_g,
                                             const float* __restrict__ adjn_g,
                                             float* __restrict__ out) {
    __shared__ float wht[8192];  // [c][j]
    __shared__ float A[1024];    // [v][j] = att value with v in i-role
    __shared__ float gt[1024];   // [j][i]
    __shared__ float adjn[1024]; // [v][i]
    __shared__ float un[32], mxl[32], El[32];
    int tid = threadIdx.x;
    int bid = blockIdx.x;
    int n = bid >> 5, tp = bid & 31;
    int m = tp >> 1, odd = tp & 1;
    const float4* src = (const float4*)(WhT + ((size_t)(n * 32 + tp)) * 8192);
#pragma unroll
    for (int k = 0; k < 8; ++k)
        ((float4*)wht)[tid + 256 * k] = src[tid + 256 * k];
    ((float4*)adjn)[tid] = ((const float4*)adjn_g)[tid];
    if (tid < 32) {
        un[tid]  = u_g[(n * 32 + tid) * 16 + m];
        mxl[tid] = mx_g[n * 32 + tid];
        El[tid]  = E_g[n * 32 + tid];
    }
    __syncthreads();
    // phase 1: attention values
    {
        int j = tid & 31, v0 = tid >> 5;
        for (int p = 0; p < 4; ++p) {
            int v = v0 + 8 * p;
            float mv = mxl[v], mj = mxl[j];
            float M = fmaxf(mv, mj);
            float Z = El[v] * expf(mv - M) + El[j] * expf(mj - M);
            float num = odd ? expf(un[j] - M) : expf(un[v] - M);
            A[v * 32 + j] = num / Z;
        }
    }
    __syncthreads();
    // phase 2: G[i,j] = sum_v adjn[v,i]*A[v,j], stored transposed gt[j][i]
    {
        int i = tid & 31, j0 = tid >> 5;
        for (int p = 0; p < 4; ++p) {
            int j = j0 + 8 * p;
            float acc = 0.f;
#pragma unroll
            for (int v = 0; v < 32; ++v)
                acc = fmaf(adjn[v * 32 + i], A[v * 32 + j], acc);
            gt[j * 32 + i] = acc;
        }
    }
    __syncthreads();
    // phase 3: out[c,i] = sum_j G[i,j]*wht[c,j], then ELU
    {
        int i = tid & 31, cg = tid >> 5;
        float greg[32];
#pragma unroll
        for (int j = 0; j < 32; ++j) greg[j] = gt[j * 32 + i];
        for (int k = 0; k < 32; ++k) {
            int c = cg * 32 + k;
            float acc = 0.f;
#pragma unroll
            for (int j8 = 0; j8 < 8; ++j8) {
                float4 w4 = ((float4*)wht)[c * 8 + j8];
                acc = fmaf(greg[4 * j8 + 0], w4.x, acc);
                acc = fmaf(greg[4 * j8 + 1], w4.y, acc);
                acc = fmaf(greg[4 * j8 + 2], w4.z, acc);
                acc = fmaf(greg[4 * j8 + 3], w4.w, acc);
            }
            float o = acc > 0.f ? acc : expm1f(acc);
            out[(((size_t)(n * 256 + c)) * 32 + tp) * 32 + i] = o;
        }
    }
}

extern "C" void kernel_launch(void* const* d_in, const int* in_sizes, int n_in,
                              void* d_out, int out_size, void* d_ws, size_t ws_size,
                              hipStream_t stream) {
    const float* h  = (const float*)d_in[0];
    const float* Wm = (const float*)d_in[1];
    const float* a  = (const float*)d_in[2];
    const float* B  = (const float*)d_in[3];
    float* out = (float*)d_out;
    float* ws  = (float*)d_ws;

    float* Wh   = ws;
    float* WhT  = ws + 1048576;
    float* u_g  = ws + 2097152;
    float* mx_g = u_g + 2048;
    float* E_g  = mx_g + 128;
    float* adjn = E_g + 128;

    k_adjnorm<<<1, 256, 0, stream>>>(B, adjn);
    k_wh<<<1024, 256, 0, stream>>>(h, Wm, Wh, WhT);
    k_softstats<<<128, 256, 0, stream>>>(Wh, a, u_g, mx_g, E_g);
    k_out<<<128, 256, 0, stream>>>(WhT, u_g, mx_g, E_g, adjn, out);
}